// Round 11
// baseline (1478.672 us; speedup 1.0000x reference)
//
#include <hip/hip_runtime.h>
#include <hip/hip_bf16.h>
#include <hip/hip_fp16.h>

#define N_NODES   100000
#define N_EDGES   3200000
#define N_FEAT    500
#define HIDDEN    128
#define N_CLASSES 64
#define K_LAYERS  10
#define NBUCK     98          // ceil(N_NODES / 1024)
#define SLU       400004      // uint2 per fp16 slice: (N_NODES+1) rows * 4
#define SLF4      400004      // float4 per fp32 h0 slice: (N_NODES+1) rows * 4

typedef __attribute__((ext_vector_type(4))) float f32x4;
typedef __attribute__((ext_vector_type(8))) _Float16 f16x8;

__device__ inline float2 h2f2(unsigned u) {
  __half2 h = *(__half2*)&u;
  return make_float2(__low2float(h), __high2float(h));
}
__device__ inline unsigned f2h2(float a, float b) {
  __half2 h = __floats2half2_rn(a, b);
  return *(unsigned*)&h;
}

// ============ CSR build via bucketed counting sort (no global scatter) ======
// Records packed as src | (dstLocal<<17); src < 2^17, dstLocal < 1024.

__global__ __launch_bounds__(256) void bucket_count_k(const int* __restrict__ dst,
                                                      int* __restrict__ bucket_cnt) {
  __shared__ int h[128];
  int t = threadIdx.x;
  if (t < 128) h[t] = 0;
  __syncthreads();
  for (int e = blockIdx.x * 256 + t; e < N_EDGES; e += gridDim.x * 256)
    atomicAdd(&h[dst[e] >> 10], 1);
  __syncthreads();
  if (t < 128 && h[t]) atomicAdd(&bucket_cnt[t], h[t]);
}

__global__ __launch_bounds__(128) void bucket_scan_k(const int* __restrict__ bucket_cnt,
                                                     int* __restrict__ bucket_base,
                                                     int* __restrict__ bcur,
                                                     int* __restrict__ offs) {
  __shared__ int sm[128];
  int t = threadIdx.x;
  int c = bucket_cnt[t];
  sm[t] = c;
  __syncthreads();
  for (int d = 1; d < 128; d <<= 1) {
    int v = (t >= d) ? sm[t - d] : 0;
    __syncthreads();
    sm[t] += v;
    __syncthreads();
  }
  int ex = sm[t] - c;  // exclusive prefix
  bucket_base[t] = ex;
  bcur[t] = ex;
  if (t == 127) bucket_base[128] = ex + c;  // == N_EDGES
  if (t == 0) offs[N_NODES] = N_EDGES;
}

#define BIN_CHUNK 12800   // 250 blocks * 12800 = 3.2M exactly
__global__ __launch_bounds__(256) void bin_scatter_k(const int* __restrict__ src,
                                                     const int* __restrict__ dst,
                                                     int* __restrict__ bcur,
                                                     int* __restrict__ binned) {
  __shared__ int h[128];
  __shared__ int hbase[128];
  int t = threadIdx.x;
  int e0 = blockIdx.x * BIN_CHUNK;
  int e1 = min(e0 + BIN_CHUNK, N_EDGES);
  if (t < 128) h[t] = 0;
  __syncthreads();
  for (int e = e0 + t; e < e1; e += 256) atomicAdd(&h[dst[e] >> 10], 1);
  __syncthreads();
  if (t < 128) {
    int c = h[t];
    hbase[t] = c ? atomicAdd(&bcur[t], c) : 0;
  }
  __syncthreads();
  if (t < 128) h[t] = 0;
  __syncthreads();
  for (int e = e0 + t; e < e1; e += 256) {
    int d = dst[e];
    int b = d >> 10;
    int pos = hbase[b] + atomicAdd(&h[b], 1);
    binned[pos] = (src[e] & 0x1FFFF) | ((d & 1023) << 17);
  }
}

__global__ __launch_bounds__(256) void bucket_fill_k(const int* __restrict__ binned,
                                                     const int* __restrict__ bucket_base,
                                                     int* __restrict__ offs,
                                                     float* __restrict__ dinv,
                                                     int* __restrict__ csr4) {
  __shared__ int cnt[1024];
  __shared__ int tsum[256];
  int b = blockIdx.x;
  int base = bucket_base[b];
  int nE = bucket_base[b + 1] - base;
  int node0 = b << 10;
  int nN = min(1024, N_NODES - node0);
  int t = threadIdx.x;
  #pragma unroll
  for (int i = 0; i < 4; ++i) cnt[t + i * 256] = 0;
  __syncthreads();
  for (int i = t; i < nE; i += 256) atomicAdd(&cnt[binned[base + i] >> 17], 1);
  __syncthreads();
  int c0 = cnt[4 * t], c1 = cnt[4 * t + 1], c2 = cnt[4 * t + 2], c3 = cnt[4 * t + 3];
  int s = c0 + c1 + c2 + c3;
  tsum[t] = s;
  __syncthreads();
  for (int d = 1; d < 256; d <<= 1) {
    int v = (t >= d) ? tsum[t - d] : 0;
    __syncthreads();
    tsum[t] += v;
    __syncthreads();
  }
  int run = tsum[t] - s;  // exclusive
  int p0 = run, p1 = run + c0, p2 = p1 + c1, p3 = p2 + c2;
  if (4 * t + 0 < nN) { offs[node0 + 4 * t + 0] = base + p0; dinv[node0 + 4 * t + 0] = rsqrtf(c0 + 1.f); }
  if (4 * t + 1 < nN) { offs[node0 + 4 * t + 1] = base + p1; dinv[node0 + 4 * t + 1] = rsqrtf(c1 + 1.f); }
  if (4 * t + 2 < nN) { offs[node0 + 4 * t + 2] = base + p2; dinv[node0 + 4 * t + 2] = rsqrtf(c2 + 1.f); }
  if (4 * t + 3 < nN) { offs[node0 + 4 * t + 3] = base + p3; dinv[node0 + 4 * t + 3] = rsqrtf(c3 + 1.f); }
  __syncthreads();
  cnt[4 * t] = p0; cnt[4 * t + 1] = p1; cnt[4 * t + 2] = p2; cnt[4 * t + 3] = p3;
  __syncthreads();
  for (int i = t; i < nE; i += 256) {
    int rec = binned[base + i];
    int p = base + atomicAdd(&cnt[rec >> 17], 1);
    csr4[p] = rec & 0x1FFFF;
  }
}

// ---------------- weight prep: fp16, pre-swizzled, K-step-chunked ------------
__global__ void prep_wsw_k(const float* __restrict__ W, ushort* __restrict__ Bsw,
                           int KTOT, int BN, int KPAD) {
  int g = blockIdx.x * 256 + threadIdx.x;
  if (g >= BN * KPAD) return;
  int chunk = BN * 64;
  int s = g / chunk;
  int r = g - s * chunk;
  int c = r >> 6;
  int q = r & 63;
  int X = (q >> 3) ^ (c & 7);
  int e = q & 7;
  int k = s * 64 + X * 8 + e;
  float v = (k < KTOT) ? W[(size_t)k * BN + c] : 0.f;
  _Float16 hv = (_Float16)v;
  Bsw[g] = *(ushort*)&hv;
}

// ---------------- fp16 MFMA GEMM core (device-only; see round-9 stub bug) ---
// CMODE: 0 = fp32 row-major, 1 = fp16 row-major, 2 = fp32 slice-major
// ([4][(N+1)*16] floats, slice = col>>4).
template<int BN, int KTOT, int KPAD, bool RELU, bool A16, int CMODE>
__device__ __forceinline__ void gemm_core(const void* Ain, const ushort* Bsw,
                                          const float* bias, void* Cout, int M) {
  constexpr int BK = 64;
  constexpr int NS = KPAD / BK;
  constexpr int NF = BN / 16;                  // n-frags per wave
  constexpr int CHUNK = BN * BK;               // ushorts per K-step
  constexpr int NL = CHUNK * 2 / (16 * 256);   // global_load_lds insts/thread
  __shared__ __align__(16) ushort Bl[2][CHUNK];

  int tid = threadIdx.x;
  int lane = tid & 63, w = tid >> 6;
  int lrow = lane & 15, lg = lane >> 4;
  int row0 = blockIdx.x * 128 + w * 32;

  const float* A32 = (const float*)Ain;
  const ushort* Ah = (const ushort*)Ain;

  f32x4 acc[2][NF];
  #pragma unroll
  for (int m = 0; m < 2; ++m)
    #pragma unroll
    for (int n = 0; n < NF; ++n) acc[m][n] = (f32x4){0.f, 0.f, 0.f, 0.f};

  #define STAGE(s, buf)                                                   \
    {                                                                     \
      const ushort* gp = Bsw + (size_t)(s) * CHUNK;                       \
      _Pragma("unroll")                                                   \
      for (int i = 0; i < NL; ++i) {                                      \
        int o = (tid + i * 256) * 8;                                      \
        __builtin_amdgcn_global_load_lds(gp + o, &Bl[buf][o], 16, 0, 0);  \
      }                                                                   \
    }

  STAGE(0, 0);
  asm volatile("s_waitcnt vmcnt(0)" ::: "memory");
  __syncthreads();

  #pragma unroll 1
  for (int s = 0; s < NS; ++s) {
    int cur = s & 1;
    if (s + 1 < NS) STAGE(s + 1, cur ^ 1);
    int kc = s * BK;
    #pragma unroll
    for (int ks = 0; ks < 2; ++ks) {
      f16x8 af[2];
      #pragma unroll
      for (int m = 0; m < 2; ++m) {
        int r = row0 + m * 16 + lrow;
        int rc = r < M ? r : M - 1;            // clamp; garbage rows unused
        int k0 = kc + ks * 32 + lg * 8;
        if (A16) {
          af[m] = *(const f16x8*)(Ah + (size_t)rc * KPAD + k0);
        } else {
          const float* ap = A32 + (size_t)rc * KTOT + k0;
          f16x8 h;
          if (k0 + 7 < KTOT) {
            float4 f0 = *(const float4*)ap;
            float4 f1 = *(const float4*)(ap + 4);
            h[0] = (_Float16)f0.x; h[1] = (_Float16)f0.y;
            h[2] = (_Float16)f0.z; h[3] = (_Float16)f0.w;
            h[4] = (_Float16)f1.x; h[5] = (_Float16)f1.y;
            h[6] = (_Float16)f1.z; h[7] = (_Float16)f1.w;
          } else {
            #pragma unroll
            for (int e = 0; e < 8; ++e)
              h[e] = (_Float16)((k0 + e < KTOT) ? ap[e] : 0.f);
          }
          af[m] = h;
        }
      }
      #pragma unroll
      for (int n = 0; n < NF; ++n) {
        int c = n * 16 + lrow;
        int ad = c * 64 + ((((ks << 2) + lg) ^ (c & 7)) << 3);  // ushort idx
        f16x8 bf = *(const f16x8*)(&Bl[cur][ad]);
        #pragma unroll
        for (int m = 0; m < 2; ++m)
          acc[m][n] = __builtin_amdgcn_mfma_f32_16x16x32_f16(af[m], bf, acc[m][n], 0, 0, 0);
      }
    }
    asm volatile("s_waitcnt vmcnt(0)" ::: "memory");
    __syncthreads();
  }
  #undef STAGE

  // epilogue: C/D layout col=lane&15, row=(lane>>4)*4+reg (verified)
  #pragma unroll
  for (int m = 0; m < 2; ++m)
    #pragma unroll
    for (int n = 0; n < NF; ++n) {
      int c = n * 16 + lrow;
      float bb = bias[c];
      #pragma unroll
      for (int r4 = 0; r4 < 4; ++r4) {
        int grow = row0 + m * 16 + lg * 4 + r4;
        if (grow < M) {
          float v = acc[m][n][r4] + bb;
          if (RELU) v = fmaxf(v, 0.f);
          if (CMODE == 0) {
            ((float*)Cout)[(size_t)grow * BN + c] = v;
          } else if (CMODE == 1) {
            _Float16 hv = (_Float16)v;
            ((ushort*)Cout)[(size_t)grow * BN + c] = *(ushort*)&hv;
          } else {
            // fp32 slice-major: slice = c>>4 (== n), ch = c&15 (== lrow)
            ((float*)Cout)[(size_t)(c >> 4) * (4 * SLF4) + (size_t)grow * 16 + (c & 15)] = v;
          }
        }
      }
    }
}

// Non-template wrappers: ordinary host stubs (round-9 stub-emission bug).
__global__ __launch_bounds__(256, 2) void gemm1_k(const float* __restrict__ A,
                                                  const ushort* __restrict__ Bsw,
                                                  const float* __restrict__ bias,
                                                  ushort* __restrict__ C, int M) {
  gemm_core<128, 500, 512, true, false, 1>(A, Bsw, bias, C, M);
}
__global__ __launch_bounds__(256, 2) void gemm2_k(const ushort* __restrict__ A,
                                                  const ushort* __restrict__ Bsw,
                                                  const float* __restrict__ bias,
                                                  float* __restrict__ C, int M) {
  gemm_core<64, 128, 128, false, true, 2>(A, Bsw, bias, C, M);
}

// ---------------- zero the pad rows (node N_NODES) of both y buffers --------
// Runs AFTER the GEMMs (y buffers overlay H; round-5 lesson). 2 bufs x 4
// slices x 4 uint2 = 32 writes; prop never writes pad rows.
__global__ void pad_zero_k(uint2* __restrict__ yA, uint2* __restrict__ yB) {
  int t = threadIdx.x;
  if (t >= 32) return;
  uint2* b = (t & 16) ? yB : yA;
  int p = (t >> 2) & 3, lc = t & 3;
  b[(size_t)p * SLU + (size_t)N_NODES * 4 + lc] = make_uint2(0, 0);
}

// ---------------- y0 = fp16(dinv * h0), slice-major [4][(N+1)*4] uint2 ------
__global__ __launch_bounds__(256) void conv_y0_k(const float4* __restrict__ h0sl4,
                                                 const float* __restrict__ dinv,
                                                 uint2* __restrict__ y16) {
  int j = blockIdx.x * 256 + threadIdx.x;   // float4/uint2 index within slice
  if (j >= N_NODES * 4) return;
  int p = blockIdx.y;
  int node = j >> 2;
  float dv = dinv[node];
  float4 h4 = h0sl4[(size_t)p * SLF4 + j];
  y16[(size_t)p * SLU + j] =
      make_uint2(f2h2(dv * h4.x, dv * h4.y), f2h2(dv * h4.z, dv * h4.w));
}

// ---------------- propagation: channel-sliced, slice-sequential -------------
// y fp16 slice-major [4][(N+1) rows x 32B]. blockIdx.y = slice (slowest-
// varying -> dispatch processes one 3.2MB slice at a time; every XCD L2
// caches it). Wave = one (node, slice): 4 lanes/edge (uint2), 16 edges per
// load, 4 loads in flight per 64-edge tile. Pad edges -> zero row N_NODES.
template<bool OUT32>
__global__ __launch_bounds__(256) void prop_s_k(const uint2* __restrict__ yin,
                                                void* __restrict__ out,
                                                const float4* __restrict__ h0sl4,
                                                const float* __restrict__ dinv,
                                                const int* __restrict__ offs,
                                                const int* __restrict__ csr4) {
  int p = blockIdx.y;
  int lane = threadIdx.x & 63;
  int wid = threadIdx.x >> 6;
  int node = (blockIdx.x << 2) + wid;
  if (node >= N_NODES) return;
  int grp = lane >> 2;   // edge subgroup 0..15
  int lc = lane & 3;     // uint2 slot (4 channels)
  const uint2* ys = yin + (size_t)p * SLU;

  float4 acc = make_float4(0.f, 0.f, 0.f, 0.f);
  int beg = offs[node], end = offs[node + 1];
  for (int e = beg; e < end; e += 64) {
    int s = (e + lane < end) ? csr4[e + lane] : N_NODES;  // pad -> zero row
    int sr[4];
    uint2 g[4];
    #pragma unroll
    for (int q = 0; q < 4; ++q) sr[q] = __shfl(s, q * 16 + grp);
    #pragma unroll
    for (int q = 0; q < 4; ++q) g[q] = ys[(size_t)sr[q] * 4 + lc];
    #pragma unroll
    for (int q = 0; q < 4; ++q) {
      float2 a = h2f2(g[q].x), b = h2f2(g[q].y);
      acc.x += a.x; acc.y += a.y; acc.z += b.x; acc.w += b.y;
    }
  }
  // merge the 16 subgroup partials (lane bits 2..5)
  #pragma unroll
  for (int off = 4; off <= 32; off <<= 1) {
    acc.x += __shfl_xor(acc.x, off);
    acc.y += __shfl_xor(acc.y, off);
    acc.z += __shfl_xor(acc.z, off);
    acc.w += __shfl_xor(acc.w, off);
  }
  if (grp == 0) {
    uint2 gs = ys[(size_t)node * 4 + lc];   // self term
    float2 a = h2f2(gs.x), b = h2f2(gs.y);
    acc.x += a.x; acc.y += a.y; acc.z += b.x; acc.w += b.y;
    float dv = dinv[node];
    float4 h4 = h0sl4[(size_t)p * SLF4 + (size_t)node * 4 + lc];
    float4 z;
    z.x = 0.9f * dv * acc.x + 0.1f * h4.x;
    z.y = 0.9f * dv * acc.y + 0.1f * h4.y;
    z.z = 0.9f * dv * acc.z + 0.1f * h4.z;
    z.w = 0.9f * dv * acc.w + 0.1f * h4.w;
    if (OUT32) {
      // fp32 row-major [N][64]: slice p covers cols p*16 + lc*4 ..+3
      ((float4*)out)[(size_t)node * 16 + p * 4 + lc] = z;
    } else {
      ((uint2*)out)[(size_t)p * SLU + (size_t)node * 4 + lc] =
          make_uint2(f2h2(dv * z.x, dv * z.y), f2h2(dv * z.z, dv * z.w));
    }
  }
}

// ---------------- softmax over 64 classes, one wave per row (in-place OK) ---
__global__ __launch_bounds__(256) void softmax_k(const float* z, float* out) {
  int lane = threadIdx.x & 63;
  int row = (blockIdx.x * 256 + threadIdx.x) >> 6;
  if (row >= N_NODES) return;
  float v = z[(size_t)row * 64 + lane];
  float m = v;
  #pragma unroll
  for (int o = 32; o > 0; o >>= 1) m = fmaxf(m, __shfl_xor(m, o));
  float ev = __expf(v - m);
  float s = ev;
  #pragma unroll
  for (int o = 32; o > 0; o >>= 1) s += __shfl_xor(s, o);
  out[(size_t)row * 64 + lane] = ev / s;
}

extern "C" void kernel_launch(void* const* d_in, const int* in_sizes, int n_in,
                              void* d_out, int out_size, void* d_ws, size_t ws_size,
                              hipStream_t stream) {
  const float* x  = (const float*)d_in[0];
  const int*   ei = (const int*)d_in[1];
  const float* W1 = (const float*)d_in[2];
  const float* b1 = (const float*)d_in[3];
  const float* W2 = (const float*)d_in[4];
  const float* b2 = (const float*)d_in[5];
  const int* src = ei;
  const int* dst = ei + N_EDGES;

  char* w = (char*)d_ws;
  // Layout (bytes):
  //   [0, 12.8M)        csr4
  //   [12.8M, 38.4M)    H fp16 (gemm1 out, dead after gemm2) -- overlaid:
  //       yA @12.8M (12,800,128), yB @25.7M (12,800,128; tail past H is fine)
  //   [38.6M, 64.2M)    binned (setup-only) -> h0sl fp32 slice-major (25.6M)
  //   [64.5M, ...)      dinv, offs, bucket arrays, swizzled fp16 weights
  // d_out: final fp32 z, then in-place softmax. No zF32 buffer needed.
  int*    csr4  = (int*)w;
  ushort* H     = (ushort*)(w + 12800000);
  uint2*  yA    = (uint2*)(w + 12800000);
  uint2*  yB    = (uint2*)(w + 25700000);
  int*    binned = (int*)(w + 38600000);
  float*  h0sl  = (float*)(w + 38600000);
  float*  dinv  = (float*)(w + 64500000);
  int*    offs  = (int*)(w + 65000000);
  int*    bucket_cnt  = (int*)(w + 66000000);   // 128 ints
  int*    bucket_base = (int*)(w + 66002048);   // 129 ints
  int*    bcur        = (int*)(w + 66004096);   // 128 ints
  ushort* w1sw  = (ushort*)(w + 66500000);      // 128 KB
  ushort* w2sw  = (ushort*)(w + 66700000);      // 16 KB

  hipMemsetAsync(bucket_cnt, 0, 128 * 4, stream);

  // ---- CSR build (bucketed counting sort) ----
  bucket_count_k<<<512, 256, 0, stream>>>(dst, bucket_cnt);
  bucket_scan_k<<<1, 128, 0, stream>>>(bucket_cnt, bucket_base, bcur, offs);
  bin_scatter_k<<<N_EDGES / BIN_CHUNK, 256, 0, stream>>>(src, dst, bcur, binned);
  bucket_fill_k<<<NBUCK, 256, 0, stream>>>(binned, bucket_base, offs, dinv, csr4);

  // ---- MLP (fp16 single-MFMA); gemm2 writes h0 fp32 slice-major ----
  prep_wsw_k<<<(128 * 512 + 255) / 256, 256, 0, stream>>>(W1, w1sw, 500, 128, 512);
  prep_wsw_k<<<(64 * 128 + 255) / 256, 256, 0, stream>>>(W2, w2sw, 128, 64, 128);
  gemm1_k<<<(N_NODES + 127) / 128, 256, 0, stream>>>(x, w1sw, b1, H, N_NODES);
  gemm2_k<<<(N_NODES + 127) / 128, 256, 0, stream>>>(H, w2sw, b2, h0sl, N_NODES);

  // Pad rows + y0 (after GEMMs: y buffers overlay H — round-5 lesson).
  pad_zero_k<<<1, 64, 0, stream>>>(yA, yB);
  conv_y0_k<<<dim3((N_NODES * 4 + 255) / 256, 4), 256, 0, stream>>>(
      (const float4*)h0sl, dinv, yA);

  // ---- 10 propagation layers, 4 channel-slices each (blockIdx.y = slice) ----
  const uint2* zi = yA;
  uint2* zo = yB;
  for (int it = 0; it < K_LAYERS - 1; ++it) {
    prop_s_k<false><<<dim3(N_NODES / 4, 4), 256, 0, stream>>>(
        zi, (void*)zo, (const float4*)h0sl, dinv, offs, csr4);
    zi = zo;
    zo = (zo == yA) ? yB : yA;
  }
  prop_s_k<true><<<dim3(N_NODES / 4, 4), 256, 0, stream>>>(
      zi, d_out, (const float4*)h0sl, dinv, offs, csr4);

  softmax_k<<<(N_NODES * 64) / 256, 256, 0, stream>>>((float*)d_out, (float*)d_out);
}

// Round 12
// 975.608 us; speedup vs baseline: 1.5156x; 1.5156x over previous
//
#include <hip/hip_runtime.h>
#include <hip/hip_bf16.h>
#include <hip/hip_fp16.h>

#define N_NODES   100000
#define N_EDGES   3200000
#define N_FEAT    500
#define HIDDEN    128
#define N_CLASSES 64
#define K_LAYERS  10
#define NBUCK     98          // ceil(N_NODES / 1024)

typedef __attribute__((ext_vector_type(4))) float f32x4;
typedef __attribute__((ext_vector_type(8))) _Float16 f16x8;

__device__ inline float2 h2f2(unsigned u) {
  __half2 h = *(__half2*)&u;
  return make_float2(__low2float(h), __high2float(h));
}
__device__ inline unsigned f2h2(float a, float b) {
  __half2 h = __floats2half2_rn(a, b);
  return *(unsigned*)&h;
}

// ============ CSR build via bucketed counting sort (no global scatter) ======
// Records packed as src | (dstLocal<<17); src < 2^17, dstLocal < 1024.

__global__ __launch_bounds__(256) void bucket_count_k(const int* __restrict__ dst,
                                                      int* __restrict__ bucket_cnt) {
  __shared__ int h[128];
  int t = threadIdx.x;
  if (t < 128) h[t] = 0;
  __syncthreads();
  for (int e = blockIdx.x * 256 + t; e < N_EDGES; e += gridDim.x * 256)
    atomicAdd(&h[dst[e] >> 10], 1);
  __syncthreads();
  if (t < 128 && h[t]) atomicAdd(&bucket_cnt[t], h[t]);
}

__global__ __launch_bounds__(128) void bucket_scan_k(const int* __restrict__ bucket_cnt,
                                                     int* __restrict__ bucket_base,
                                                     int* __restrict__ bcur,
                                                     int* __restrict__ offs) {
  __shared__ int sm[128];
  int t = threadIdx.x;
  int c = bucket_cnt[t];
  sm[t] = c;
  __syncthreads();
  for (int d = 1; d < 128; d <<= 1) {
    int v = (t >= d) ? sm[t - d] : 0;
    __syncthreads();
    sm[t] += v;
    __syncthreads();
  }
  int ex = sm[t] - c;  // exclusive prefix
  bucket_base[t] = ex;
  bcur[t] = ex;
  if (t == 127) bucket_base[128] = ex + c;  // == N_EDGES
  if (t == 0) offs[N_NODES] = N_EDGES;
}

#define BIN_CHUNK 12800   // 250 blocks * 12800 = 3.2M exactly
__global__ __launch_bounds__(256) void bin_scatter_k(const int* __restrict__ src,
                                                     const int* __restrict__ dst,
                                                     int* __restrict__ bcur,
                                                     int* __restrict__ binned) {
  __shared__ int h[128];
  __shared__ int hbase[128];
  int t = threadIdx.x;
  int e0 = blockIdx.x * BIN_CHUNK;
  int e1 = min(e0 + BIN_CHUNK, N_EDGES);
  if (t < 128) h[t] = 0;
  __syncthreads();
  for (int e = e0 + t; e < e1; e += 256) atomicAdd(&h[dst[e] >> 10], 1);
  __syncthreads();
  if (t < 128) {
    int c = h[t];
    hbase[t] = c ? atomicAdd(&bcur[t], c) : 0;
  }
  __syncthreads();
  if (t < 128) h[t] = 0;
  __syncthreads();
  for (int e = e0 + t; e < e1; e += 256) {
    int d = dst[e];
    int b = d >> 10;
    int pos = hbase[b] + atomicAdd(&h[b], 1);
    binned[pos] = (src[e] & 0x1FFFF) | ((d & 1023) << 17);
  }
}

__global__ __launch_bounds__(256) void bucket_fill_k(const int* __restrict__ binned,
                                                     const int* __restrict__ bucket_base,
                                                     int* __restrict__ offs,
                                                     float* __restrict__ dinv,
                                                     int* __restrict__ csr4) {
  __shared__ int cnt[1024];
  __shared__ int tsum[256];
  int b = blockIdx.x;
  int base = bucket_base[b];
  int nE = bucket_base[b + 1] - base;
  int node0 = b << 10;
  int nN = min(1024, N_NODES - node0);
  int t = threadIdx.x;
  #pragma unroll
  for (int i = 0; i < 4; ++i) cnt[t + i * 256] = 0;
  __syncthreads();
  for (int i = t; i < nE; i += 256) atomicAdd(&cnt[binned[base + i] >> 17], 1);
  __syncthreads();
  int c0 = cnt[4 * t], c1 = cnt[4 * t + 1], c2 = cnt[4 * t + 2], c3 = cnt[4 * t + 3];
  int s = c0 + c1 + c2 + c3;
  tsum[t] = s;
  __syncthreads();
  for (int d = 1; d < 256; d <<= 1) {
    int v = (t >= d) ? tsum[t - d] : 0;
    __syncthreads();
    tsum[t] += v;
    __syncthreads();
  }
  int run = tsum[t] - s;  // exclusive
  int p0 = run, p1 = run + c0, p2 = p1 + c1, p3 = p2 + c2;
  if (4 * t + 0 < nN) { offs[node0 + 4 * t + 0] = base + p0; dinv[node0 + 4 * t + 0] = rsqrtf(c0 + 1.f); }
  if (4 * t + 1 < nN) { offs[node0 + 4 * t + 1] = base + p1; dinv[node0 + 4 * t + 1] = rsqrtf(c1 + 1.f); }
  if (4 * t + 2 < nN) { offs[node0 + 4 * t + 2] = base + p2; dinv[node0 + 4 * t + 2] = rsqrtf(c2 + 1.f); }
  if (4 * t + 3 < nN) { offs[node0 + 4 * t + 3] = base + p3; dinv[node0 + 4 * t + 3] = rsqrtf(c3 + 1.f); }
  __syncthreads();
  cnt[4 * t] = p0; cnt[4 * t + 1] = p1; cnt[4 * t + 2] = p2; cnt[4 * t + 3] = p3;
  __syncthreads();
  for (int i = t; i < nE; i += 256) {
    int rec = binned[base + i];
    int p = base + atomicAdd(&cnt[rec >> 17], 1);
    csr4[p] = rec & 0x1FFFF;
  }
}

// ---------------- weight prep: fp16, pre-swizzled, K-step-chunked ------------
__global__ void prep_wsw_k(const float* __restrict__ W, ushort* __restrict__ Bsw,
                           int KTOT, int BN, int KPAD) {
  int g = blockIdx.x * 256 + threadIdx.x;
  if (g >= BN * KPAD) return;
  int chunk = BN * 64;
  int s = g / chunk;
  int r = g - s * chunk;
  int c = r >> 6;
  int q = r & 63;
  int X = (q >> 3) ^ (c & 7);
  int e = q & 7;
  int k = s * 64 + X * 8 + e;
  float v = (k < KTOT) ? W[(size_t)k * BN + c] : 0.f;
  _Float16 hv = (_Float16)v;
  Bsw[g] = *(ushort*)&hv;
}

// ---------------- fp16 MFMA GEMM core (device-only; round-9 stub bug) -------
template<int BN, int KTOT, int KPAD, bool RELU, bool A16, bool C16>
__device__ __forceinline__ void gemm_core(const void* Ain, const ushort* Bsw,
                                          const float* bias, void* Cout, int M) {
  constexpr int BK = 64;
  constexpr int NS = KPAD / BK;
  constexpr int NF = BN / 16;                  // n-frags per wave
  constexpr int CHUNK = BN * BK;               // ushorts per K-step
  constexpr int NL = CHUNK * 2 / (16 * 256);   // global_load_lds insts/thread
  __shared__ __align__(16) ushort Bl[2][CHUNK];

  int tid = threadIdx.x;
  int lane = tid & 63, w = tid >> 6;
  int lrow = lane & 15, lg = lane >> 4;
  int row0 = blockIdx.x * 128 + w * 32;

  const float* A32 = (const float*)Ain;
  const ushort* Ah = (const ushort*)Ain;

  f32x4 acc[2][NF];
  #pragma unroll
  for (int m = 0; m < 2; ++m)
    #pragma unroll
    for (int n = 0; n < NF; ++n) acc[m][n] = (f32x4){0.f, 0.f, 0.f, 0.f};

  #define STAGE(s, buf)                                                   \
    {                                                                     \
      const ushort* gp = Bsw + (size_t)(s) * CHUNK;                       \
      _Pragma("unroll")                                                   \
      for (int i = 0; i < NL; ++i) {                                      \
        int o = (tid + i * 256) * 8;                                      \
        __builtin_amdgcn_global_load_lds(gp + o, &Bl[buf][o], 16, 0, 0);  \
      }                                                                   \
    }

  STAGE(0, 0);
  asm volatile("s_waitcnt vmcnt(0)" ::: "memory");
  __syncthreads();

  #pragma unroll 1
  for (int s = 0; s < NS; ++s) {
    int cur = s & 1;
    if (s + 1 < NS) STAGE(s + 1, cur ^ 1);
    int kc = s * BK;
    #pragma unroll
    for (int ks = 0; ks < 2; ++ks) {
      f16x8 af[2];
      #pragma unroll
      for (int m = 0; m < 2; ++m) {
        int r = row0 + m * 16 + lrow;
        int rc = r < M ? r : M - 1;            // clamp; garbage rows unused
        int k0 = kc + ks * 32 + lg * 8;
        if (A16) {
          af[m] = *(const f16x8*)(Ah + (size_t)rc * KPAD + k0);
        } else {
          const float* ap = A32 + (size_t)rc * KTOT + k0;
          f16x8 h;
          if (k0 + 7 < KTOT) {
            float4 f0 = *(const float4*)ap;
            float4 f1 = *(const float4*)(ap + 4);
            h[0] = (_Float16)f0.x; h[1] = (_Float16)f0.y;
            h[2] = (_Float16)f0.z; h[3] = (_Float16)f0.w;
            h[4] = (_Float16)f1.x; h[5] = (_Float16)f1.y;
            h[6] = (_Float16)f1.z; h[7] = (_Float16)f1.w;
          } else {
            #pragma unroll
            for (int e = 0; e < 8; ++e)
              h[e] = (_Float16)((k0 + e < KTOT) ? ap[e] : 0.f);
          }
          af[m] = h;
        }
      }
      #pragma unroll
      for (int n = 0; n < NF; ++n) {
        int c = n * 16 + lrow;
        int ad = c * 64 + ((((ks << 2) + lg) ^ (c & 7)) << 3);  // ushort idx
        f16x8 bf = *(const f16x8*)(&Bl[cur][ad]);
        #pragma unroll
        for (int m = 0; m < 2; ++m)
          acc[m][n] = __builtin_amdgcn_mfma_f32_16x16x32_f16(af[m], bf, acc[m][n], 0, 0, 0);
      }
    }
    asm volatile("s_waitcnt vmcnt(0)" ::: "memory");
    __syncthreads();
  }
  #undef STAGE

  // epilogue: C/D layout col=lane&15, row=(lane>>4)*4+reg (verified)
  #pragma unroll
  for (int m = 0; m < 2; ++m)
    #pragma unroll
    for (int n = 0; n < NF; ++n) {
      int c = n * 16 + lrow;
      float bb = bias[c];
      #pragma unroll
      for (int r4 = 0; r4 < 4; ++r4) {
        int grow = row0 + m * 16 + lg * 4 + r4;
        if (grow < M) {
          float v = acc[m][n][r4] + bb;
          if (RELU) v = fmaxf(v, 0.f);
          if (C16) {
            _Float16 hv = (_Float16)v;
            ((ushort*)Cout)[(size_t)grow * BN + c] = *(ushort*)&hv;
          } else {
            ((float*)Cout)[(size_t)grow * BN + c] = v;
          }
        }
      }
    }
}

// Non-template wrappers: ordinary host stubs (round-9 stub-emission bug).
__global__ __launch_bounds__(256, 2) void gemm1_k(const float* __restrict__ A,
                                                  const ushort* __restrict__ Bsw,
                                                  const float* __restrict__ bias,
                                                  ushort* __restrict__ C, int M) {
  gemm_core<128, 500, 512, true, false, true>(A, Bsw, bias, C, M);
}
__global__ __launch_bounds__(256, 2) void gemm2_k(const ushort* __restrict__ A,
                                                  const ushort* __restrict__ Bsw,
                                                  const float* __restrict__ bias,
                                                  float* __restrict__ C, int M) {
  gemm_core<64, 128, 128, false, true, false>(A, Bsw, bias, C, M);
}

// ---- y0 = fp16(dinv*h0) and h016 = fp16(h0), row-major [N][64] (uint4) -----
__global__ __launch_bounds__(256) void conv_y0_k(const float* __restrict__ h0,
                                                 const float* __restrict__ dinv,
                                                 uint4* __restrict__ y16,
                                                 uint4* __restrict__ h16) {
  int j = blockIdx.x * 256 + threadIdx.x;   // one uint4 (8 halves) per thread
  if (j >= N_NODES * 8) return;
  int node = j >> 3;
  float dv = dinv[node];
  const float4* hp = (const float4*)(h0 + (size_t)j * 8);
  float4 a = hp[0], b = hp[1];
  y16[j] = make_uint4(f2h2(dv * a.x, dv * a.y), f2h2(dv * a.z, dv * a.w),
                      f2h2(dv * b.x, dv * b.y), f2h2(dv * b.z, dv * b.w));
  h16[j] = make_uint4(f2h2(a.x, a.y), f2h2(a.z, a.w),
                      f2h2(b.x, b.y), f2h2(b.z, b.w));
}

// ---------------- propagation: fp16 y-gather, uint4 lanes -------------------
// y = dinv*z stored fp16 [N+1][64] (row 128B; row N_NODES is a zero pad row).
// Wave = one node: 8 lanes per edge-row (16B/lane); 32 edges (4 loads) in
// flight. Layers 0..8 use fp16 h016; final layer uses fp32 h0 (exact additive).
template<bool OUT32>
__global__ __launch_bounds__(256) void prop_k(const uint4* __restrict__ yin,
                                              void* __restrict__ out,
                                              const uint4* __restrict__ h016,
                                              const float* __restrict__ h0f,
                                              const float* __restrict__ dinv,
                                              const int* __restrict__ offs,
                                              const int* __restrict__ csr4) {
  int lane = threadIdx.x & 63;
  int wid = threadIdx.x >> 6;
  int node = (blockIdx.x << 2) + wid;
  if (node >= N_NODES) return;
  int grp = lane >> 3;   // edge slot 0..7
  int lc = lane & 7;     // uint4 slot within 128B row

  float acc[8];
  #pragma unroll
  for (int i = 0; i < 8; ++i) acc[i] = 0.f;

  int beg = offs[node], end = offs[node + 1];
  for (int e = beg; e < end; e += 64) {
    int s = (e + lane < end) ? csr4[e + lane] : N_NODES;  // pad -> zero row
    int cnt = min(64, end - e);
    for (int j = 0; j < cnt; j += 32) {
      int sr[4];
      uint4 g[4];
      #pragma unroll
      for (int q = 0; q < 4; ++q) sr[q] = __shfl(s, j + 8 * q + grp);
      #pragma unroll
      for (int q = 0; q < 4; ++q) g[q] = yin[(size_t)sr[q] * 8 + lc];
      #pragma unroll
      for (int q = 0; q < 4; ++q) {
        float2 p0 = h2f2(g[q].x), p1 = h2f2(g[q].y);
        float2 p2 = h2f2(g[q].z), p3 = h2f2(g[q].w);
        acc[0] += p0.x; acc[1] += p0.y; acc[2] += p1.x; acc[3] += p1.y;
        acc[4] += p2.x; acc[5] += p2.y; acc[6] += p3.x; acc[7] += p3.y;
      }
    }
  }
  // merge the 8 edge-slot partials (lane bits 3,4,5)
  #pragma unroll
  for (int off = 8; off <= 32; off <<= 1)
    #pragma unroll
    for (int i = 0; i < 8; ++i) acc[i] += __shfl_xor(acc[i], off);

  if (grp == 0) {
    // self term
    uint4 gs = yin[(size_t)node * 8 + lc];
    {
      float2 p0 = h2f2(gs.x), p1 = h2f2(gs.y), p2 = h2f2(gs.z), p3 = h2f2(gs.w);
      acc[0] += p0.x; acc[1] += p0.y; acc[2] += p1.x; acc[3] += p1.y;
      acc[4] += p2.x; acc[5] += p2.y; acc[6] += p3.x; acc[7] += p3.y;
    }
    float dv = dinv[node];
    float z[8];
    if (OUT32) {
      const float4* hp = (const float4*)(h0f + (size_t)node * 64 + lc * 8);
      float4 hA = hp[0], hB = hp[1];
      z[0] = 0.9f * dv * acc[0] + 0.1f * hA.x;
      z[1] = 0.9f * dv * acc[1] + 0.1f * hA.y;
      z[2] = 0.9f * dv * acc[2] + 0.1f * hA.z;
      z[3] = 0.9f * dv * acc[3] + 0.1f * hA.w;
      z[4] = 0.9f * dv * acc[4] + 0.1f * hB.x;
      z[5] = 0.9f * dv * acc[5] + 0.1f * hB.y;
      z[6] = 0.9f * dv * acc[6] + 0.1f * hB.z;
      z[7] = 0.9f * dv * acc[7] + 0.1f * hB.w;
      float4* zp = (float4*)out + (size_t)node * 16 + lc * 2;
      zp[0] = make_float4(z[0], z[1], z[2], z[3]);
      zp[1] = make_float4(z[4], z[5], z[6], z[7]);
    } else {
      uint4 hh = h016[(size_t)node * 8 + lc];
      float2 h0p = h2f2(hh.x), h1p = h2f2(hh.y), h2p = h2f2(hh.z), h3p = h2f2(hh.w);
      z[0] = 0.9f * dv * acc[0] + 0.1f * h0p.x;
      z[1] = 0.9f * dv * acc[1] + 0.1f * h0p.y;
      z[2] = 0.9f * dv * acc[2] + 0.1f * h1p.x;
      z[3] = 0.9f * dv * acc[3] + 0.1f * h1p.y;
      z[4] = 0.9f * dv * acc[4] + 0.1f * h2p.x;
      z[5] = 0.9f * dv * acc[5] + 0.1f * h2p.y;
      z[6] = 0.9f * dv * acc[6] + 0.1f * h3p.x;
      z[7] = 0.9f * dv * acc[7] + 0.1f * h3p.y;
      ((uint4*)out)[(size_t)node * 8 + lc] =
          make_uint4(f2h2(dv * z[0], dv * z[1]), f2h2(dv * z[2], dv * z[3]),
                     f2h2(dv * z[4], dv * z[5]), f2h2(dv * z[6], dv * z[7]));
    }
  }
}

// ---------------- softmax over 64 classes, one wave per row ----------------
__global__ __launch_bounds__(256) void softmax_k(const float* __restrict__ z,
                                                 float* __restrict__ out) {
  int lane = threadIdx.x & 63;
  int row = (blockIdx.x * 256 + threadIdx.x) >> 6;
  if (row >= N_NODES) return;
  float v = z[(size_t)row * 64 + lane];
  float m = v;
  #pragma unroll
  for (int o = 32; o > 0; o >>= 1) m = fmaxf(m, __shfl_xor(m, o));
  float ev = __expf(v - m);
  float s = ev;
  #pragma unroll
  for (int o = 32; o > 0; o >>= 1) s += __shfl_xor(s, o);
  out[(size_t)row * 64 + lane] = ev / s;
}

extern "C" void kernel_launch(void* const* d_in, const int* in_sizes, int n_in,
                              void* d_out, int out_size, void* d_ws, size_t ws_size,
                              hipStream_t stream) {
  const float* x  = (const float*)d_in[0];
  const int*   ei = (const int*)d_in[1];
  const float* W1 = (const float*)d_in[2];
  const float* b1 = (const float*)d_in[3];
  const float* W2 = (const float*)d_in[4];
  const float* b2 = (const float*)d_in[5];
  const int* src = ei;
  const int* dst = ei + N_EDGES;

  char* w = (char*)d_ws;
  // Layout (bytes; ws is ~800MB so non-overlapping where convenient):
  //   [0, 12.8M)        csr4
  //   [12.8M, 38.4M)    H fp16 (gemm1 out, dead after gemm2) -- overlaid:
  //       yA @12.8M (+pad row), yB @25.7M (+pad row)
  //   [38.6M, 64.2M)    binned (setup-only) / zF32 (final z)
  //   [64.5M, 67M)      dinv, offs, bucket arrays, swizzled fp16 weights
  //   [70M, 82.8M)      h016 (fp16 h0, layers 0..8)
  int*    csr4  = (int*)w;
  ushort* H     = (ushort*)(w + 12800000);
  uint4*  yA    = (uint4*)(w + 12800000);
  uint4*  yB    = (uint4*)(w + 25700000);
  float*  zF32  = (float*)(w + 38600000);
  int*    binned = (int*)(w + 38600000);
  float*  dinv  = (float*)(w + 64500000);
  int*    offs  = (int*)(w + 65000000);
  int*    bucket_cnt  = (int*)(w + 66000000);   // 128 ints
  int*    bucket_base = (int*)(w + 66002048);   // 129 ints
  int*    bcur        = (int*)(w + 66004096);   // 128 ints
  ushort* w1sw  = (ushort*)(w + 66500000);      // 128 KB
  ushort* w2sw  = (ushort*)(w + 66700000);      // 16 KB
  uint4*  h016  = (uint4*)(w + 70000000);       // 12.8 MB
  float* h0 = (float*)d_out;  // fp32 [N][64]; dead once last layer reads it

  hipMemsetAsync(bucket_cnt, 0, 128 * 4, stream);

  // ---- CSR build (bucketed counting sort) ----
  bucket_count_k<<<512, 256, 0, stream>>>(dst, bucket_cnt);
  bucket_scan_k<<<1, 128, 0, stream>>>(bucket_cnt, bucket_base, bcur, offs);
  bin_scatter_k<<<N_EDGES / BIN_CHUNK, 256, 0, stream>>>(src, dst, bcur, binned);
  bucket_fill_k<<<NBUCK, 256, 0, stream>>>(binned, bucket_base, offs, dinv, csr4);

  // ---- MLP (fp16 single-MFMA) ----
  prep_wsw_k<<<(128 * 512 + 255) / 256, 256, 0, stream>>>(W1, w1sw, 500, 128, 512);
  prep_wsw_k<<<(64 * 128 + 255) / 256, 256, 0, stream>>>(W2, w2sw, 128, 64, 128);
  gemm1_k<<<(N_NODES + 127) / 128, 256, 0, stream>>>(x, w1sw, b1, H, N_NODES);
  gemm2_k<<<(N_NODES + 127) / 128, 256, 0, stream>>>(H, w2sw, b2, h0, N_NODES);

  // Zero the pad rows (index N_NODES) of both fp16 y buffers. MUST happen
  // after the GEMMs: yA/yB overlay H and gemm1 would clobber the pads
  // (round 5's absmax=0.99 bug). prop_k never writes pad rows.
  hipMemsetAsync((char*)yA + (size_t)N_NODES * 128, 0, 128, stream);
  hipMemsetAsync((char*)yB + (size_t)N_NODES * 128, 0, 128, stream);

  conv_y0_k<<<(N_NODES * 8 + 255) / 256, 256, 0, stream>>>(h0, dinv, yA, h016);

  const uint4* zi = yA;
  uint4* zo = yB;
  for (int it = 0; it < K_LAYERS - 1; ++it) {
    prop_k<false><<<(N_NODES + 3) / 4, 256, 0, stream>>>(
        zi, (void*)zo, h016, h0, dinv, offs, csr4);
    zi = zo;
    zo = (zo == yA) ? yB : yA;
  }
  prop_k<true><<<(N_NODES + 3) / 4, 256, 0, stream>>>(
      zi, (void*)zF32, h016, h0, dinv, offs, csr4);

  softmax_k<<<(N_NODES * 64) / 256, 256, 0, stream>>>(zF32, (float*)d_out);
}

// Round 13
// 958.910 us; speedup vs baseline: 1.5420x; 1.0174x over previous
//
#include <hip/hip_runtime.h>
#include <hip/hip_bf16.h>
#include <hip/hip_fp16.h>

#define N_NODES   100000
#define N_EDGES   3200000
#define N_FEAT    500
#define HIDDEN    128
#define N_CLASSES 64
#define K_LAYERS  10
#define NBUCK     98          // ceil(N_NODES / 1024)

typedef __attribute__((ext_vector_type(4))) float f32x4;
typedef __attribute__((ext_vector_type(8))) _Float16 f16x8;

__device__ inline float2 h2f2(unsigned u) {
  __half2 h = *(__half2*)&u;
  return make_float2(__low2float(h), __high2float(h));
}
__device__ inline unsigned f2h2(float a, float b) {
  __half2 h = __floats2half2_rn(a, b);
  return *(unsigned*)&h;
}

// ============ CSR build via bucketed counting sort (no global scatter) ======
// Records packed as src | (dstLocal<<17); src < 2^17, dstLocal < 1024.

__global__ __launch_bounds__(256) void bucket_count_k(const int* __restrict__ dst,
                                                      int* __restrict__ bucket_cnt) {
  __shared__ int h[128];
  int t = threadIdx.x;
  if (t < 128) h[t] = 0;
  __syncthreads();
  for (int e = blockIdx.x * 256 + t; e < N_EDGES; e += gridDim.x * 256)
    atomicAdd(&h[dst[e] >> 10], 1);
  __syncthreads();
  if (t < 128 && h[t]) atomicAdd(&bucket_cnt[t], h[t]);
}

__global__ __launch_bounds__(128) void bucket_scan_k(const int* __restrict__ bucket_cnt,
                                                     int* __restrict__ bucket_base,
                                                     int* __restrict__ bcur,
                                                     int* __restrict__ offs) {
  __shared__ int sm[128];
  int t = threadIdx.x;
  int c = bucket_cnt[t];
  sm[t] = c;
  __syncthreads();
  for (int d = 1; d < 128; d <<= 1) {
    int v = (t >= d) ? sm[t - d] : 0;
    __syncthreads();
    sm[t] += v;
    __syncthreads();
  }
  int ex = sm[t] - c;  // exclusive prefix
  bucket_base[t] = ex;
  bcur[t] = ex;
  if (t == 127) bucket_base[128] = ex + c;  // == N_EDGES
  if (t == 0) offs[N_NODES] = N_EDGES;
}

#define BIN_CHUNK 12800   // 250 blocks * 12800 = 3.2M exactly
__global__ __launch_bounds__(256) void bin_scatter_k(const int* __restrict__ src,
                                                     const int* __restrict__ dst,
                                                     int* __restrict__ bcur,
                                                     int* __restrict__ binned) {
  __shared__ int h[128];
  __shared__ int hbase[128];
  int t = threadIdx.x;
  int e0 = blockIdx.x * BIN_CHUNK;
  int e1 = min(e0 + BIN_CHUNK, N_EDGES);
  if (t < 128) h[t] = 0;
  __syncthreads();
  for (int e = e0 + t; e < e1; e += 256) atomicAdd(&h[dst[e] >> 10], 1);
  __syncthreads();
  if (t < 128) {
    int c = h[t];
    hbase[t] = c ? atomicAdd(&bcur[t], c) : 0;
  }
  __syncthreads();
  if (t < 128) h[t] = 0;
  __syncthreads();
  for (int e = e0 + t; e < e1; e += 256) {
    int d = dst[e];
    int b = d >> 10;
    int pos = hbase[b] + atomicAdd(&h[b], 1);
    binned[pos] = (src[e] & 0x1FFFF) | ((d & 1023) << 17);
  }
}

__global__ __launch_bounds__(256) void bucket_fill_k(const int* __restrict__ binned,
                                                     const int* __restrict__ bucket_base,
                                                     int* __restrict__ offs,
                                                     float* __restrict__ dinv,
                                                     int* __restrict__ csr4) {
  __shared__ int cnt[1024];
  __shared__ int tsum[256];
  int b = blockIdx.x;
  int base = bucket_base[b];
  int nE = bucket_base[b + 1] - base;
  int node0 = b << 10;
  int nN = min(1024, N_NODES - node0);
  int t = threadIdx.x;
  #pragma unroll
  for (int i = 0; i < 4; ++i) cnt[t + i * 256] = 0;
  __syncthreads();
  for (int i = t; i < nE; i += 256) atomicAdd(&cnt[binned[base + i] >> 17], 1);
  __syncthreads();
  int c0 = cnt[4 * t], c1 = cnt[4 * t + 1], c2 = cnt[4 * t + 2], c3 = cnt[4 * t + 3];
  int s = c0 + c1 + c2 + c3;
  tsum[t] = s;
  __syncthreads();
  for (int d = 1; d < 256; d <<= 1) {
    int v = (t >= d) ? tsum[t - d] : 0;
    __syncthreads();
    tsum[t] += v;
    __syncthreads();
  }
  int run = tsum[t] - s;  // exclusive
  int p0 = run, p1 = run + c0, p2 = p1 + c1, p3 = p2 + c2;
  if (4 * t + 0 < nN) { offs[node0 + 4 * t + 0] = base + p0; dinv[node0 + 4 * t + 0] = rsqrtf(c0 + 1.f); }
  if (4 * t + 1 < nN) { offs[node0 + 4 * t + 1] = base + p1; dinv[node0 + 4 * t + 1] = rsqrtf(c1 + 1.f); }
  if (4 * t + 2 < nN) { offs[node0 + 4 * t + 2] = base + p2; dinv[node0 + 4 * t + 2] = rsqrtf(c2 + 1.f); }
  if (4 * t + 3 < nN) { offs[node0 + 4 * t + 3] = base + p3; dinv[node0 + 4 * t + 3] = rsqrtf(c3 + 1.f); }
  __syncthreads();
  cnt[4 * t] = p0; cnt[4 * t + 1] = p1; cnt[4 * t + 2] = p2; cnt[4 * t + 3] = p3;
  __syncthreads();
  for (int i = t; i < nE; i += 256) {
    int rec = binned[base + i];
    int p = base + atomicAdd(&cnt[rec >> 17], 1);
    csr4[p] = rec & 0x1FFFF;
  }
}

// ---------------- weight prep: fp16, pre-swizzled, K-step-chunked ------------
__global__ void prep_wsw_k(const float* __restrict__ W, ushort* __restrict__ Bsw,
                           int KTOT, int BN, int KPAD) {
  int g = blockIdx.x * 256 + threadIdx.x;
  if (g >= BN * KPAD) return;
  int chunk = BN * 64;
  int s = g / chunk;
  int r = g - s * chunk;
  int c = r >> 6;
  int q = r & 63;
  int X = (q >> 3) ^ (c & 7);
  int e = q & 7;
  int k = s * 64 + X * 8 + e;
  float v = (k < KTOT) ? W[(size_t)k * BN + c] : 0.f;
  _Float16 hv = (_Float16)v;
  Bsw[g] = *(ushort*)&hv;
}

// ---------------- fp16 MFMA GEMM core (device-only; round-9 stub bug) -------
// CMODE: 1 = fp16 row-major C. 2 = fused epilogue: fp32 h0 -> Cout, plus
// y16 = fp16(dinv*v) and h016 = fp16(v) (replaces conv_y0_k; numerics
// identical — same fp32 v rounded the same way).
template<int BN, int KTOT, int KPAD, bool RELU, bool A16, int CMODE>
__device__ __forceinline__ void gemm_core(const void* Ain, const ushort* Bsw,
                                          const float* bias, void* Cout, int M,
                                          const float* dinv, ushort* Yp,
                                          ushort* Hp) {
  constexpr int BK = 64;
  constexpr int NS = KPAD / BK;
  constexpr int NF = BN / 16;                  // n-frags per wave
  constexpr int CHUNK = BN * BK;               // ushorts per K-step
  constexpr int NL = CHUNK * 2 / (16 * 256);   // global_load_lds insts/thread
  __shared__ __align__(16) ushort Bl[2][CHUNK];

  int tid = threadIdx.x;
  int lane = tid & 63, w = tid >> 6;
  int lrow = lane & 15, lg = lane >> 4;
  int row0 = blockIdx.x * 128 + w * 32;

  const float* A32 = (const float*)Ain;
  const ushort* Ah = (const ushort*)Ain;

  f32x4 acc[2][NF];
  #pragma unroll
  for (int m = 0; m < 2; ++m)
    #pragma unroll
    for (int n = 0; n < NF; ++n) acc[m][n] = (f32x4){0.f, 0.f, 0.f, 0.f};

  #define STAGE(s, buf)                                                   \
    {                                                                     \
      const ushort* gp = Bsw + (size_t)(s) * CHUNK;                       \
      _Pragma("unroll")                                                   \
      for (int i = 0; i < NL; ++i) {                                      \
        int o = (tid + i * 256) * 8;                                      \
        __builtin_amdgcn_global_load_lds(gp + o, &Bl[buf][o], 16, 0, 0);  \
      }                                                                   \
    }

  STAGE(0, 0);
  asm volatile("s_waitcnt vmcnt(0)" ::: "memory");
  __syncthreads();

  #pragma unroll 1
  for (int s = 0; s < NS; ++s) {
    int cur = s & 1;
    if (s + 1 < NS) STAGE(s + 1, cur ^ 1);
    int kc = s * BK;
    #pragma unroll
    for (int ks = 0; ks < 2; ++ks) {
      f16x8 af[2];
      #pragma unroll
      for (int m = 0; m < 2; ++m) {
        int r = row0 + m * 16 + lrow;
        int rc = r < M ? r : M - 1;            // clamp; garbage rows unused
        int k0 = kc + ks * 32 + lg * 8;
        if (A16) {
          af[m] = *(const f16x8*)(Ah + (size_t)rc * KPAD + k0);
        } else {
          const float* ap = A32 + (size_t)rc * KTOT + k0;
          f16x8 h;
          if (k0 + 7 < KTOT) {
            float4 f0 = *(const float4*)ap;
            float4 f1 = *(const float4*)(ap + 4);
            h[0] = (_Float16)f0.x; h[1] = (_Float16)f0.y;
            h[2] = (_Float16)f0.z; h[3] = (_Float16)f0.w;
            h[4] = (_Float16)f1.x; h[5] = (_Float16)f1.y;
            h[6] = (_Float16)f1.z; h[7] = (_Float16)f1.w;
          } else {
            #pragma unroll
            for (int e = 0; e < 8; ++e)
              h[e] = (_Float16)((k0 + e < KTOT) ? ap[e] : 0.f);
          }
          af[m] = h;
        }
      }
      #pragma unroll
      for (int n = 0; n < NF; ++n) {
        int c = n * 16 + lrow;
        int ad = c * 64 + ((((ks << 2) + lg) ^ (c & 7)) << 3);  // ushort idx
        f16x8 bf = *(const f16x8*)(&Bl[cur][ad]);
        #pragma unroll
        for (int m = 0; m < 2; ++m)
          acc[m][n] = __builtin_amdgcn_mfma_f32_16x16x32_f16(af[m], bf, acc[m][n], 0, 0, 0);
      }
    }
    asm volatile("s_waitcnt vmcnt(0)" ::: "memory");
    __syncthreads();
  }
  #undef STAGE

  // epilogue: C/D layout col=lane&15, row=(lane>>4)*4+reg (verified)
  #pragma unroll
  for (int m = 0; m < 2; ++m)
    #pragma unroll
    for (int n = 0; n < NF; ++n) {
      int c = n * 16 + lrow;
      float bb = bias[c];
      #pragma unroll
      for (int r4 = 0; r4 < 4; ++r4) {
        int grow = row0 + m * 16 + lg * 4 + r4;
        if (grow < M) {
          float v = acc[m][n][r4] + bb;
          if (RELU) v = fmaxf(v, 0.f);
          if (CMODE == 1) {
            _Float16 hv = (_Float16)v;
            ((ushort*)Cout)[(size_t)grow * BN + c] = *(ushort*)&hv;
          } else {
            float dv = dinv[grow];
            ((float*)Cout)[(size_t)grow * BN + c] = v;       // h0 fp32
            _Float16 hy = (_Float16)(dv * v);
            _Float16 hh = (_Float16)v;
            Yp[(size_t)grow * BN + c] = *(ushort*)&hy;       // y0 fp16
            Hp[(size_t)grow * BN + c] = *(ushort*)&hh;       // h0 fp16
          }
        }
      }
    }
}

// Non-template wrappers: ordinary host stubs (round-9 stub-emission bug).
__global__ __launch_bounds__(256, 2) void gemm1_k(const float* __restrict__ A,
                                                  const ushort* __restrict__ Bsw,
                                                  const float* __restrict__ bias,
                                                  ushort* __restrict__ C, int M) {
  gemm_core<128, 500, 512, true, false, 1>(A, Bsw, bias, C, M, nullptr, nullptr, nullptr);
}
// gemm2 also zeroes the pad rows (node N_NODES) of both y buffers (block 0)
// and emits y0/h016 from its epilogue (conv_y0_k retired).
__global__ __launch_bounds__(256, 2) void gemm2_k(const ushort* __restrict__ A,
                                                  const ushort* __restrict__ Bsw,
                                                  const float* __restrict__ bias,
                                                  float* __restrict__ C, int M,
                                                  const float* __restrict__ dinv,
                                                  ushort* __restrict__ Yp,
                                                  ushort* __restrict__ Hp,
                                                  uint4* __restrict__ padA,
                                                  uint4* __restrict__ padB) {
  if (blockIdx.x == 0 && threadIdx.x < 16) {
    uint4 z = make_uint4(0, 0, 0, 0);
    if (threadIdx.x < 8) padA[threadIdx.x] = z;
    else padB[threadIdx.x - 8] = z;
  }
  gemm_core<64, 128, 128, false, true, 2>(A, Bsw, bias, C, M, dinv, Yp, Hp);
}

// ---------------- propagation: fp16 y-gather, uint4 lanes -------------------
// y = dinv*z stored fp16 [N+1][64] (row 128B; row N_NODES is a zero pad row).
// Wave = one node: 8 lanes per edge-row (16B/lane); 32 edges (4 loads) in
// flight. Layers 0..8: fp16 h016, fp16 y out. Final layer (SMAX): fp32 h0
// additive, fused softmax (grp-0's 8 lanes hold the full 64-ch row; 3-offset
// shfl_xor for max/sum), writes probabilities to d_out in-place over h0
// (same-row read-then-write within one wave -> safe).
template<bool SMAX>
__global__ __launch_bounds__(256) void prop_k(const uint4* __restrict__ yin,
                                              void* __restrict__ out,
                                              const uint4* __restrict__ h016,
                                              const float* __restrict__ h0f,
                                              const float* __restrict__ dinv,
                                              const int* __restrict__ offs,
                                              const int* __restrict__ csr4) {
  int lane = threadIdx.x & 63;
  int wid = threadIdx.x >> 6;
  int node = (blockIdx.x << 2) + wid;
  if (node >= N_NODES) return;
  int grp = lane >> 3;   // edge slot 0..7
  int lc = lane & 7;     // uint4 slot within 128B row

  float acc[8];
  #pragma unroll
  for (int i = 0; i < 8; ++i) acc[i] = 0.f;

  int beg = offs[node], end = offs[node + 1];
  for (int e = beg; e < end; e += 64) {
    int s = (e + lane < end) ? csr4[e + lane] : N_NODES;  // pad -> zero row
    int cnt = min(64, end - e);
    for (int j = 0; j < cnt; j += 32) {
      int sr[4];
      uint4 g[4];
      #pragma unroll
      for (int q = 0; q < 4; ++q) sr[q] = __shfl(s, j + 8 * q + grp);
      #pragma unroll
      for (int q = 0; q < 4; ++q) g[q] = yin[(size_t)sr[q] * 8 + lc];
      #pragma unroll
      for (int q = 0; q < 4; ++q) {
        float2 p0 = h2f2(g[q].x), p1 = h2f2(g[q].y);
        float2 p2 = h2f2(g[q].z), p3 = h2f2(g[q].w);
        acc[0] += p0.x; acc[1] += p0.y; acc[2] += p1.x; acc[3] += p1.y;
        acc[4] += p2.x; acc[5] += p2.y; acc[6] += p3.x; acc[7] += p3.y;
      }
    }
  }
  // merge the 8 edge-slot partials (lane bits 3,4,5)
  #pragma unroll
  for (int off = 8; off <= 32; off <<= 1)
    #pragma unroll
    for (int i = 0; i < 8; ++i) acc[i] += __shfl_xor(acc[i], off);

  if (grp == 0) {
    // self term
    uint4 gs = yin[(size_t)node * 8 + lc];
    {
      float2 p0 = h2f2(gs.x), p1 = h2f2(gs.y), p2 = h2f2(gs.z), p3 = h2f2(gs.w);
      acc[0] += p0.x; acc[1] += p0.y; acc[2] += p1.x; acc[3] += p1.y;
      acc[4] += p2.x; acc[5] += p2.y; acc[6] += p3.x; acc[7] += p3.y;
    }
    float dv = dinv[node];
    float z[8];
    if (SMAX) {
      const float4* hp = (const float4*)(h0f + (size_t)node * 64 + lc * 8);
      float4 hA = hp[0], hB = hp[1];
      z[0] = 0.9f * dv * acc[0] + 0.1f * hA.x;
      z[1] = 0.9f * dv * acc[1] + 0.1f * hA.y;
      z[2] = 0.9f * dv * acc[2] + 0.1f * hA.z;
      z[3] = 0.9f * dv * acc[3] + 0.1f * hA.w;
      z[4] = 0.9f * dv * acc[4] + 0.1f * hB.x;
      z[5] = 0.9f * dv * acc[5] + 0.1f * hB.y;
      z[6] = 0.9f * dv * acc[6] + 0.1f * hB.z;
      z[7] = 0.9f * dv * acc[7] + 0.1f * hB.w;
      // fused softmax: 8 lanes (lc=0..7) hold the full 64-channel row
      float m = z[0];
      #pragma unroll
      for (int i = 1; i < 8; ++i) m = fmaxf(m, z[i]);
      #pragma unroll
      for (int o = 1; o <= 4; o <<= 1) m = fmaxf(m, __shfl_xor(m, o));
      float ev[8], ssum = 0.f;
      #pragma unroll
      for (int i = 0; i < 8; ++i) { ev[i] = __expf(z[i] - m); ssum += ev[i]; }
      #pragma unroll
      for (int o = 1; o <= 4; o <<= 1) ssum += __shfl_xor(ssum, o);
      float inv = 1.f / ssum;
      float4* zp = (float4*)out + (size_t)node * 16 + lc * 2;
      zp[0] = make_float4(ev[0] * inv, ev[1] * inv, ev[2] * inv, ev[3] * inv);
      zp[1] = make_float4(ev[4] * inv, ev[5] * inv, ev[6] * inv, ev[7] * inv);
    } else {
      uint4 hh = h016[(size_t)node * 8 + lc];
      float2 h0p = h2f2(hh.x), h1p = h2f2(hh.y), h2p = h2f2(hh.z), h3p = h2f2(hh.w);
      z[0] = 0.9f * dv * acc[0] + 0.1f * h0p.x;
      z[1] = 0.9f * dv * acc[1] + 0.1f * h0p.y;
      z[2] = 0.9f * dv * acc[2] + 0.1f * h1p.x;
      z[3] = 0.9f * dv * acc[3] + 0.1f * h1p.y;
      z[4] = 0.9f * dv * acc[4] + 0.1f * h2p.x;
      z[5] = 0.9f * dv * acc[5] + 0.1f * h2p.y;
      z[6] = 0.9f * dv * acc[6] + 0.1f * h3p.x;
      z[7] = 0.9f * dv * acc[7] + 0.1f * h3p.y;
      ((uint4*)out)[(size_t)node * 8 + lc] =
          make_uint4(f2h2(dv * z[0], dv * z[1]), f2h2(dv * z[2], dv * z[3]),
                     f2h2(dv * z[4], dv * z[5]), f2h2(dv * z[6], dv * z[7]));
    }
  }
}

extern "C" void kernel_launch(void* const* d_in, const int* in_sizes, int n_in,
                              void* d_out, int out_size, void* d_ws, size_t ws_size,
                              hipStream_t stream) {
  const float* x  = (const float*)d_in[0];
  const int*   ei = (const int*)d_in[1];
  const float* W1 = (const float*)d_in[2];
  const float* b1 = (const float*)d_in[3];
  const float* W2 = (const float*)d_in[4];
  const float* b2 = (const float*)d_in[5];
  const int* src = ei;
  const int* dst = ei + N_EDGES;

  char* w = (char*)d_ws;
  // Layout (bytes; ws ~800MB, no overlays needed anymore):
  //   [0, 12.8M)        csr4
  //   [12.8M, 38.4M)    H fp16 (gemm1 out; read by gemm2 — nothing overlays it)
  //   [38.6M, 51.4M)    binned (setup-only)
  //   [64.5M, 67M)      dinv, offs, bucket arrays, swizzled fp16 weights
  //   [70M, 82.8M)      h016 (fp16 h0, layers 0..8)
  //   [83M, 95.8M)      yA (+pad row)   [96M, 108.8M) yB (+pad row)
  // d_out: h0 fp32 (gemm2) -> final prop reads it and overwrites with probs.
  int*    csr4  = (int*)w;
  ushort* H     = (ushort*)(w + 12800000);
  int*    binned = (int*)(w + 38600000);
  float*  dinv  = (float*)(w + 64500000);
  int*    offs  = (int*)(w + 65000000);
  int*    bucket_cnt  = (int*)(w + 66000000);   // 128 ints
  int*    bucket_base = (int*)(w + 66002048);   // 129 ints
  int*    bcur        = (int*)(w + 66004096);   // 128 ints
  ushort* w1sw  = (ushort*)(w + 66500000);      // 128 KB
  ushort* w2sw  = (ushort*)(w + 66700000);      // 16 KB
  uint4*  h016  = (uint4*)(w + 70000000);       // 12.8 MB
  uint4*  yA    = (uint4*)(w + 83000000);       // 12.8 MB + pad row
  uint4*  yB    = (uint4*)(w + 96000000);       // 12.8 MB + pad row
  float* h0 = (float*)d_out;  // fp32 [N][64]; consumed in-place by final prop

  hipMemsetAsync(bucket_cnt, 0, 128 * 4, stream);

  // ---- CSR build (bucketed counting sort) ----
  bucket_count_k<<<512, 256, 0, stream>>>(dst, bucket_cnt);
  bucket_scan_k<<<1, 128, 0, stream>>>(bucket_cnt, bucket_base, bcur, offs);
  bin_scatter_k<<<N_EDGES / BIN_CHUNK, 256, 0, stream>>>(src, dst, bcur, binned);
  bucket_fill_k<<<NBUCK, 256, 0, stream>>>(binned, bucket_base, offs, dinv, csr4);

  // ---- MLP (fp16 single-MFMA); gemm2 fuses h0/y0/h016 emission + pads ----
  prep_wsw_k<<<(128 * 512 + 255) / 256, 256, 0, stream>>>(W1, w1sw, 500, 128, 512);
  prep_wsw_k<<<(64 * 128 + 255) / 256, 256, 0, stream>>>(W2, w2sw, 128, 64, 128);
  gemm1_k<<<(N_NODES + 127) / 128, 256, 0, stream>>>(x, w1sw, b1, H, N_NODES);
  gemm2_k<<<(N_NODES + 127) / 128, 256, 0, stream>>>(
      H, w2sw, b2, h0, N_NODES, dinv, (ushort*)yA, (ushort*)h016,
      yA + (size_t)N_NODES * 8, yB + (size_t)N_NODES * 8);

  // ---- 10 propagation layers; final fuses fp32 h0 + softmax -> d_out ----
  const uint4* zi = yA;
  uint4* zo = yB;
  for (int it = 0; it < K_LAYERS - 1; ++it) {
    prop_k<false><<<(N_NODES + 3) / 4, 256, 0, stream>>>(
        zi, (void*)zo, h016, nullptr, dinv, offs, csr4);
    zi = zo;
    zo = (zo == yA) ? yB : yA;
  }
  prop_k<true><<<(N_NODES + 3) / 4, 256, 0, stream>>>(
      zi, d_out, h016, (const float*)d_out, dinv, offs, csr4);
}